// Round 3
// baseline (72.764 us; speedup 1.0000x reference)
//
#include <hip/hip_runtime.h>
#include <math.h>

// Tropical max/min-plus pseudo-matmul.
// out[b,u] = max_f(x[b,f] + w[f,u]) for u<128, min_f otherwise.
//
// R15 = R14 with the REAL spill cause fixed.
// R14 post-mortem: plain __launch_bounds__(512) still gave VGPR_Count=128.
// Cause: the allocator budgets VGPRs for the LDS-derived occupancy. 64KB LDS
// of the 160KB/CU pool -> 2 blocks/CU fit -> 4 waves/SIMD -> budget 512/4 =
// 128 VGPR, and the ~207-live pipeline spills ~80 regs (FETCH 6.4MB vs 4.6
// ideal, WRITE 6.7 vs 2.1, VALUBusy 1.9%). That 2-blocks/CU occupancy is
// unreachable anyway: grid = 256 blocks = 1 block/CU.
// Fix (two belts, both stating "1 block/CU, 2 waves/SIMD" to the allocator):
//   1. LDS inflated to 96KB (only first 64KB used) -> floor(160/96)=1 block
//      -> LDS-derived occupancy 2 waves/SIMD -> VGPR budget 256.
//   2. __attribute__((amdgpu_waves_per_eu(2,2))) pins it explicitly.
// No runtime cost: we already run exactly 1 block/CU.
//
// R13 idea (still untested fairly, kept): lane-half k-split (lanes<32:
// k in [kb,kb+32), lanes>=32: [kb+32,kb+64)), U=8 units/lane (u0=(lane&31)*8)
// -> 32 fma per x-b128 -> 64 b128/wave (was 128) -> LDS pipe ~2.6us, under
// the 5.5us VALU floor. k-halves merged via v_permlane32_swap_b32 (VALU),
// then the 8-slot LDS tree. 2-way broadcast alias of the halves = 1cyc/read
// (benign, m136). Sign folded into x (af=a*sgn; fma(w,sgn,af)) -- exact.
// VGPR budget: acc 64 + x 2x32 + w 2x32 + addr ~= 207 of 256.

#define FEAT  512
#define UNITS 256
#define BR    8          // rows per block
#define KW    64         // k per wave (32 per lane-half)
#define NW    8          // waves per block
#define NS    8          // quad-steps per wave (each covers 4 k per half)
#define LDSF  24576      // 96KB declared; first 16KB = x tile, 64KB epilogue

__device__ __forceinline__ float max3(float a, float b, float c) {
    return fmaxf(fmaxf(a, b), c);   // v_max3_f32
}

// 8 ds_read_b128 (rows 0..7); 2 distinct addrs per wave (one per k-half),
// 128 B apart -> same banks, 2-way broadcast = ~free (m136).
__device__ __forceinline__ void load_xstep(const float* __restrict__ lds, int xbase, int s,
                                           float4* __restrict__ xb) {
    #pragma unroll
    for (int r = 0; r < BR; ++r)
        xb[r] = *(const float4*)&lds[r * FEAT + xbase + s * 4];
}

// 8 global dwordx4: w[k][u0..u0+7] for the step's 4 k values (per lane-half)
__device__ __forceinline__ void load_wstep(const float* __restrict__ wp, int s,
                                           float4* __restrict__ wb) {
    #pragma unroll
    for (int k = 0; k < 4; ++k) {
        wb[2 * k]     = *(const float4*)(wp + (size_t)(s * 4 + k) * UNITS);
        wb[2 * k + 1] = *(const float4*)(wp + (size_t)(s * 4 + k) * UNITS + 4);
    }
}

// per step: 32 mul (x sign-fold) + 256 fma + 128 max3 = 416 VALU inst
__device__ __forceinline__ void compute_step(const float4* __restrict__ xb,
                                             const float4* __restrict__ wq,
                                             float sgn, float4* __restrict__ acc) {
    #pragma unroll
    for (int r = 0; r < BR; ++r) {
        const float4 a  = xb[r];
        const float4 af = make_float4(a.x * sgn, a.y * sgn, a.z * sgn, a.w * sgn);
        #pragma unroll
        for (int g = 0; g < 2; ++g) {       // unit group u0 / u0+4
            const float4 w0 = wq[0 + g];
            const float4 w1 = wq[2 + g];
            const float4 w2 = wq[4 + g];
            const float4 w3 = wq[6 + g];
            float4 A = acc[r * 2 + g];
            A.x = max3(A.x, fmaf(w0.x, sgn, af.x), fmaf(w1.x, sgn, af.y));
            A.x = max3(A.x, fmaf(w2.x, sgn, af.z), fmaf(w3.x, sgn, af.w));
            A.y = max3(A.y, fmaf(w0.y, sgn, af.x), fmaf(w1.y, sgn, af.y));
            A.y = max3(A.y, fmaf(w2.y, sgn, af.z), fmaf(w3.y, sgn, af.w));
            A.z = max3(A.z, fmaf(w0.z, sgn, af.x), fmaf(w1.z, sgn, af.y));
            A.z = max3(A.z, fmaf(w2.z, sgn, af.z), fmaf(w3.z, sgn, af.w));
            A.w = max3(A.w, fmaf(w0.w, sgn, af.x), fmaf(w1.w, sgn, af.y));
            A.w = max3(A.w, fmaf(w2.w, sgn, af.z), fmaf(w3.w, sgn, af.w));
            acc[r * 2 + g] = A;
        }
    }
}

// merge k-halves: lane l gets max(v_l, v_{l^32}) via VALU half-swap (no LDS)
__device__ __forceinline__ float half_swap_max(float v) {
    float a = v, b = v;
    asm("v_permlane32_swap_b32 %0, %1" : "+v"(a), "+v"(b));
    return fmaxf(a, b);
}

__global__ __launch_bounds__(512)
__attribute__((amdgpu_waves_per_eu(2, 2)))
void tropical_kernel(const float* __restrict__ x,
                     const float* __restrict__ w,
                     float* __restrict__ out) {
    __shared__ float lds[LDSF];   // 96KB declared -> 1 block/CU -> 256 VGPR budget
    const int tid  = threadIdx.x;
    const int lane = tid & 63;
    const int wv   = __builtin_amdgcn_readfirstlane(tid >> 6);  // 0..7
    const int h    = lane >> 5;                 // k-half within the wave
    const int u0   = (lane & 31) * 8;           // 0..248, 8 units/lane
    const float sgn = ((lane & 31) < 16) ? 1.0f : -1.0f;  // u0<128 -> max half
    const int row0 = blockIdx.x * BR;
    const int kb   = wv * KW;
    const int xbase = kb + h * 32;              // this half's k origin

    // ---- stage x tile (8 rows x 512 = 16 KB), two float4 per thread ----
    {
        const float4* src = (const float4*)(x + (size_t)row0 * FEAT);
        ((float4*)lds)[tid]       = src[tid];
        ((float4*)lds)[tid + 512] = src[tid + 512];
    }

    const float* wp = w + (size_t)xbase * UNITS + u0;

    float4 acc[BR * 2];
    #pragma unroll
    for (int i = 0; i < BR * 2; ++i)
        acc[i] = make_float4(-__builtin_inff(), -__builtin_inff(),
                             -__builtin_inff(), -__builtin_inff());

    // prologue w prefetch overlaps the staging barrier
    float4 xA[BR], xB[BR], wA[8], wB[8];
    load_wstep(wp, 0, wA);

    __syncthreads();   // x tile visible
    load_xstep(lds, xbase, 0, xA);

    // ---- software-pipelined main loop: x AND w one step ahead ----
    #pragma unroll 1
    for (int s = 0; s < NS; s += 2) {
        load_wstep(wp, s + 1, wB);
        load_xstep(lds, xbase, s + 1, xB);
        compute_step(xA, wA, sgn, acc);      // covers the B-loads
        if (s + 2 < NS) {
            load_wstep(wp, s + 2, wA);
            load_xstep(lds, xbase, s + 2, xA);
        }
        compute_step(xB, wB, sgn, acc);      // covers the A-loads
    }

    // ---- merge the two k-halves in-register (VALU, not LDS) ----
    #pragma unroll
    for (int i = 0; i < BR * 2; ++i) {
        acc[i].x = half_swap_max(acc[i].x);
        acc[i].y = half_swap_max(acc[i].y);
        acc[i].z = half_swap_max(acc[i].z);
        acc[i].w = half_swap_max(acc[i].w);
    }

    // ---- combine 8 wave-partials via LDS (reuses x region) ----
    __syncthreads();   // all waves done reading x tile
    if (lane < 32) {   // halves now hold identical data; low half writes
        #pragma unroll
        for (int r = 0; r < BR; ++r) {
            *(float4*)&lds[(wv * BR + r) * UNITS + u0]     = acc[r * 2];
            *(float4*)&lds[(wv * BR + r) * UNITS + u0 + 4] = acc[r * 2 + 1];
        }
    }
    __syncthreads();

    // thread -> float4 of output: r = tid>>6 (0..7), units uo..uo+3
    const int r  = tid >> 6;
    const int uo = (tid & 63) * 4;
    float4 v = *(const float4*)&lds[(0 * BR + r) * UNITS + uo];
    #pragma unroll
    for (int j = 1; j < NW; ++j) {
        const float4 p = *(const float4*)&lds[(j * BR + r) * UNITS + uo];
        v.x = fmaxf(v.x, p.x);
        v.y = fmaxf(v.y, p.y);
        v.z = fmaxf(v.z, p.z);
        v.w = fmaxf(v.w, p.w);
    }
    const float so = (uo < 128) ? 1.0f : -1.0f;    // undo negation for min half
    *(float4*)&out[(size_t)(row0 + r) * UNITS + uo] =
        make_float4(v.x * so, v.y * so, v.z * so, v.w * so);
}

extern "C" void kernel_launch(void* const* d_in, const int* in_sizes, int n_in,
                              void* d_out, int out_size, void* d_ws, size_t ws_size,
                              hipStream_t stream) {
    const float* x = (const float*)d_in[0];   // (2048, 512)
    const float* w = (const float*)d_in[1];   // (512, 256)
    float* out = (float*)d_out;               // (2048, 256)

    // 256 blocks x 8 waves = 2048 waves = 2/SIMD, 1 block/CU; ILP-pipelined
    tropical_kernel<<<dim3(2048 / BR), dim3(512), 0, stream>>>(x, w, out);
}

// Round 4
// 70.648 us; speedup vs baseline: 1.0299x; 1.0299x over previous
//
#include <hip/hip_runtime.h>
#include <math.h>

// Tropical max/min-plus pseudo-matmul.
// out[b,u] = max_f(x[b,f] + w[f,u]) for u<128, min_f otherwise.
//
// R16 = R15 with the lane-split's two structural defects fixed.
// R15 post-mortem: spill fixed (kernel fell out of top-5; first dispatch
// <41us vs 131us) but dur_us 72.8 == spilled rounds, ~4.4us worse than R12.
// The regression is inherent to the R13 unit-INTERLEAVE (u0=(lane&31)*8):
//   (a) w-loads uncoalesced: 16B used per 32B span, 2 rows per instruction
//       -> 2x L2 granules/inst vs R12's contiguous 1KB.
//   (b) 32 sign-fold muls/step still paid.
// Fix: unit-GROUP split. Lane covers ug=(lane&31)*4 (group0) and ug+128
// (group1). Each w-load instr = contiguous 512B per lane-half (fully-used
// 64B granules). Group0 = all-max units, group1 = all-min units -> sign is
// compile-time PER INSTRUCTION: g0 = a+w (v_add), g1 = -a-w (v_sub with
// free VOP3 neg modifier). Fold muls gone: 384 VALU/step (was 416).
// Exactness: RN is sign-symmetric, so max(-a-w) == -min(a+w) bit-exact.
//
// Retained from R13/R15:
//   - lane-half k-split (lanes<32: k in [xb,xb+32), lanes>=32: +32):
//     64 x-b128/wave (was 128 in R12) -> LDS pipe ~2.6us < VALU ~5.1us.
//   - k-halves merged via v_permlane32_swap_b32 (VALU, not LDS).
//   - 96KB LDS declaration + waves_per_eu(2,2): tells the allocator the
//     truth (1 block/CU, 2 waves/SIMD) -> 256 VGPR budget, no spills
//     (R14's 64KB decl implied 2 blocks/CU -> 128 budget -> 80 spilled).
// VGPR budget: acc 64 + x 2x32 + w 2x32 + addr ~= 205 of 256.

#define FEAT  512
#define UNITS 256
#define BR    8          // rows per block
#define KW    64         // k per wave (32 per lane-half)
#define NW    8          // waves per block
#define NS    8          // steps per wave (each covers 4 k per half)
#define LDSF  24576      // 96KB declared; first 16KB = x tile, 64KB epilogue

__device__ __forceinline__ float max3(float a, float b, float c) {
    return fmaxf(fmaxf(a, b), c);   // v_max3_f32
}

// 8 ds_read_b128 (rows 0..7); 2 distinct addrs per wave (one per k-half),
// 128 B apart -> same banks, 2-way broadcast = ~free (m136).
__device__ __forceinline__ void load_xstep(const float* __restrict__ lds, int xbase, int s,
                                           float4* __restrict__ xb) {
    #pragma unroll
    for (int r = 0; r < BR; ++r)
        xb[r] = *(const float4*)&lds[r * FEAT + xbase + s * 4];
}

// 8 global dwordx4: w[k][ug..ug+3] and w[k][ug+128..ug+131] for 4 k values.
// Each instruction: two contiguous 512B half-wave segments (coalesced).
__device__ __forceinline__ void load_wstep(const float* __restrict__ wp, int s,
                                           float4* __restrict__ wb) {
    #pragma unroll
    for (int k = 0; k < 4; ++k) {
        wb[2 * k]     = *(const float4*)(wp + (size_t)(s * 4 + k) * UNITS);
        wb[2 * k + 1] = *(const float4*)(wp + (size_t)(s * 4 + k) * UNITS + 128);
    }
}

// per step: 256 add/sub + 128 max3 = 384 VALU inst (no sign-fold muls)
__device__ __forceinline__ void compute_step(const float4* __restrict__ xb,
                                             const float4* __restrict__ wq,
                                             float4* __restrict__ acc) {
    #pragma unroll
    for (int r = 0; r < BR; ++r) {
        const float4 a = xb[r];
        {   // group 0: units ug..ug+3 (max half): val = a + w
            const float4 w0 = wq[0], w1 = wq[2], w2 = wq[4], w3 = wq[6];
            float4 A = acc[r * 2];
            A.x = max3(A.x, a.x + w0.x, a.y + w1.x);
            A.x = max3(A.x, a.z + w2.x, a.w + w3.x);
            A.y = max3(A.y, a.x + w0.y, a.y + w1.y);
            A.y = max3(A.y, a.z + w2.y, a.w + w3.y);
            A.z = max3(A.z, a.x + w0.z, a.y + w1.z);
            A.z = max3(A.z, a.z + w2.z, a.w + w3.z);
            A.w = max3(A.w, a.x + w0.w, a.y + w1.w);
            A.w = max3(A.w, a.z + w2.w, a.w + w3.w);
            acc[r * 2] = A;
        }
        {   // group 1: units ug+128.. (min half): val = -(a+w) = (-a)-w
            const float4 w0 = wq[1], w1 = wq[3], w2 = wq[5], w3 = wq[7];
            float4 A = acc[r * 2 + 1];
            A.x = max3(A.x, -a.x - w0.x, -a.y - w1.x);
            A.x = max3(A.x, -a.z - w2.x, -a.w - w3.x);
            A.y = max3(A.y, -a.x - w0.y, -a.y - w1.y);
            A.y = max3(A.y, -a.z - w2.y, -a.w - w3.y);
            A.z = max3(A.z, -a.x - w0.z, -a.y - w1.z);
            A.z = max3(A.z, -a.z - w2.z, -a.w - w3.z);
            A.w = max3(A.w, -a.x - w0.w, -a.y - w1.w);
            A.w = max3(A.w, -a.z - w2.w, -a.w - w3.w);
            acc[r * 2 + 1] = A;
        }
    }
}

// merge k-halves: lane l gets max(v_l, v_{l^32}) via VALU half-swap (no LDS)
__device__ __forceinline__ float half_swap_max(float v) {
    float a = v, b = v;
    asm("v_permlane32_swap_b32 %0, %1" : "+v"(a), "+v"(b));
    return fmaxf(a, b);
}

__global__ __launch_bounds__(512)
__attribute__((amdgpu_waves_per_eu(2, 2)))
void tropical_kernel(const float* __restrict__ x,
                     const float* __restrict__ w,
                     float* __restrict__ out) {
    __shared__ float lds[LDSF];   // 96KB declared -> 1 block/CU -> 256 VGPR budget
    const int tid  = threadIdx.x;
    const int lane = tid & 63;
    const int wv   = __builtin_amdgcn_readfirstlane(tid >> 6);  // 0..7
    const int h    = lane >> 5;                 // k-half within the wave
    const int ug   = (lane & 31) * 4;           // group0 unit base; group1 = +128
    const int row0 = blockIdx.x * BR;
    const int kb   = wv * KW;
    const int xbase = kb + h * 32;              // this half's k origin

    // ---- stage x tile (8 rows x 512 = 16 KB), two float4 per thread ----
    {
        const float4* src = (const float4*)(x + (size_t)row0 * FEAT);
        ((float4*)lds)[tid]       = src[tid];
        ((float4*)lds)[tid + 512] = src[tid + 512];
    }

    const float* wp = w + (size_t)xbase * UNITS + ug;

    float4 acc[BR * 2];
    #pragma unroll
    for (int i = 0; i < BR * 2; ++i)
        acc[i] = make_float4(-__builtin_inff(), -__builtin_inff(),
                             -__builtin_inff(), -__builtin_inff());

    // prologue w prefetch overlaps the staging barrier
    float4 xA[BR], xB[BR], wA[8], wB[8];
    load_wstep(wp, 0, wA);

    __syncthreads();   // x tile visible
    load_xstep(lds, xbase, 0, xA);

    // ---- software-pipelined main loop: x AND w one step ahead ----
    #pragma unroll 1
    for (int s = 0; s < NS; s += 2) {
        load_wstep(wp, s + 1, wB);
        load_xstep(lds, xbase, s + 1, xB);
        compute_step(xA, wA, acc);           // covers the B-loads
        if (s + 2 < NS) {
            load_wstep(wp, s + 2, wA);
            load_xstep(lds, xbase, s + 2, xA);
        }
        compute_step(xB, wB, acc);           // covers the A-loads
    }

    // ---- merge the two k-halves in-register (VALU, not LDS) ----
    #pragma unroll
    for (int i = 0; i < BR * 2; ++i) {
        acc[i].x = half_swap_max(acc[i].x);
        acc[i].y = half_swap_max(acc[i].y);
        acc[i].z = half_swap_max(acc[i].z);
        acc[i].w = half_swap_max(acc[i].w);
    }

    // ---- combine 8 wave-partials via LDS (reuses x region) ----
    __syncthreads();   // all waves done reading x tile
    if (lane < 32) {   // halves hold identical data; low half writes both groups
        #pragma unroll
        for (int r = 0; r < BR; ++r) {
            *(float4*)&lds[(wv * BR + r) * UNITS + ug]       = acc[r * 2];
            *(float4*)&lds[(wv * BR + r) * UNITS + ug + 128] = acc[r * 2 + 1];
        }
    }
    __syncthreads();

    // thread -> float4 of output: r = tid>>6 (0..7), units uo..uo+3
    const int r  = tid >> 6;
    const int uo = (tid & 63) * 4;
    float4 v = *(const float4*)&lds[(0 * BR + r) * UNITS + uo];
    #pragma unroll
    for (int j = 1; j < NW; ++j) {
        const float4 p = *(const float4*)&lds[(j * BR + r) * UNITS + uo];
        v.x = fmaxf(v.x, p.x);
        v.y = fmaxf(v.y, p.y);
        v.z = fmaxf(v.z, p.z);
        v.w = fmaxf(v.w, p.w);
    }
    const float so = (uo < 128) ? 1.0f : -1.0f;    // undo negation for min half
    *(float4*)&out[(size_t)(row0 + r) * UNITS + uo] =
        make_float4(v.x * so, v.y * so, v.z * so, v.w * so);
}

extern "C" void kernel_launch(void* const* d_in, const int* in_sizes, int n_in,
                              void* d_out, int out_size, void* d_ws, size_t ws_size,
                              hipStream_t stream) {
    const float* x = (const float*)d_in[0];   // (2048, 512)
    const float* w = (const float*)d_in[1];   // (512, 256)
    float* out = (float*)d_out;               // (2048, 256)

    // 256 blocks x 8 waves = 2048 waves = 2/SIMD, 1 block/CU; ILP-pipelined
    tropical_kernel<<<dim3(2048 / BR), dim3(512), 0, stream>>>(x, w, out);
}